// Round 8
// baseline (77.943 us; speedup 1.0000x reference)
//
#include <hip/hip_runtime.h>

// ASTDecoder: batched GCN on a fixed banded graph (i<->i+1, i<->i+2), 2048
// graphs x 256 nodes. Only 9 distinct rows/graph survive 3 layers (8 boundary
// + 1 interior; tail mirrors head). History: 102 -> 92 -> 78 -> 73 -> 65.6 ->
// 66.4us. Write floor ~39us (fill: 6.9 TB/s). R6/R7 showed store type (NT vs
// plain) and store-wave count don't matter: write phase stuck at ~5 TB/s.
// R8 tests the last structural difference vs the fill kernel: store FRONTIER.
// Kernel B now grid-strides the whole 268 MB flat (like fill) instead of
// giving each block a private contiguous 128 KB window; values are gathered
// per-element from the L2/L3-resident 9.4 MB row table.

#define NB   2048
#define EMB  256
#define HID  64
#define ODIM 128
#define NN   256
#define NROW 9
#define MG   4            // graphs per block (kernel A)
#define NBLK (NB / MG)

typedef float f32x4 __attribute__((ext_vector_type(4)));

__device__ __forceinline__ float dinvf(int j) {
  // deg: node0=3, node1=4, nodes 2..253=5 (mirror symmetric); only j<=9 used.
  if (j == 0) return 0.57735026918962576f;  // 1/sqrt(3)
  if (j == 1) return 0.5f;                  // 1/sqrt(4)
  return 0.44721359549995794f;              // 1/sqrt(5)
}

struct Smem {
  float e[MG][EMB];        // staged embeddings
  float red[8][MG][HID];   // init split-K partials
  float X8s[MG][4][HID];   // interior chain levels (interior waves)
  float X8b[MG][4][HID];   // boundary waves' private chain copy
  float Xb[MG][8][HID];    // boundary rows
};

// One boundary-path GCN layer (intra-wave dataflow only).
template <int L, int ND_IN>
__device__ __forceinline__ void boundary_layer(Smem& s, int g, int j,
                                               const float* __restrict__ convW,
                                               const float* __restrict__ convB) {
  const float* W  = convW + L * HID * HID;
  const float* bb = convB + L * HID;

  // interior-row chain step: g8 = X8^L @ W (col j), pre-bias/pre-relu
  float g8 = 0.f;
  #pragma unroll
  for (int k0 = 0; k0 < HID; k0 += 4) {
    const f32x4 xv = *reinterpret_cast<const f32x4*>(&s.X8b[g][L][k0]);
    g8 = fmaf(xv[0], W[(k0 + 0) * HID + j], g8);
    g8 = fmaf(xv[1], W[(k0 + 1) * HID + j], g8);
    g8 = fmaf(xv[2], W[(k0 + 2) * HID + j], g8);
    g8 = fmaf(xv[3], W[(k0 + 3) * HID + j], g8);
  }
  s.X8b[g][L + 1][j] = fmaxf(g8 + bb[j], 0.f);

  // boundary G rows (register accumulators)
  float accR[ND_IN > 0 ? ND_IN : 1];
  #pragma unroll
  for (int r = 0; r < (ND_IN > 0 ? ND_IN : 1); ++r) accR[r] = 0.f;
  if constexpr (ND_IN > 0) {
    #pragma unroll
    for (int k0 = 0; k0 < HID; k0 += 4) {
      float w[4];
      #pragma unroll
      for (int c = 0; c < 4; ++c) w[c] = W[(k0 + c) * HID + j];
      #pragma unroll
      for (int r = 0; r < ND_IN; ++r) {
        const f32x4 xv = *reinterpret_cast<const f32x4*>(&s.Xb[g][r][k0]);
        accR[r] = fmaf(xv[0], w[0], accR[r]);
        accR[r] = fmaf(xv[1], w[1], accR[r]);
        accR[r] = fmaf(xv[2], w[2], accR[r]);
        accR[r] = fmaf(xv[3], w[3], accR[r]);
      }
    }
  }

  // banded mix
  constexpr int NDN = (ND_IN + 2 < 4) ? 4 : (ND_IN + 2);
  float xnew[NDN];
  #pragma unroll
  for (int i = 0; i < NDN; ++i) {
    const float di = dinvf(i);
    float acc = 0.f;
    #pragma unroll
    for (int jj = (i >= 2 ? i - 2 : 0); jj <= i + 2; ++jj) {
      const float v = (jj < ND_IN) ? accR[jj] : g8;
      acc = fmaf(di * dinvf(jj), v, acc);
    }
    xnew[i] = fmaxf(acc + bb[j], 0.f);
  }
  #pragma unroll
  for (int i = 0; i < NDN; ++i) s.Xb[g][i][j] = xnew[i];
}

// ---------------- Kernel A: distinct-row table ----------------
__global__ __launch_bounds__(512) void compute_rows(
    const float* __restrict__ emb,
    const float* __restrict__ W_emb,
    const float* __restrict__ b_emb,
    const float* __restrict__ convW,
    const float* __restrict__ convB,
    const float* __restrict__ Wout,
    const float* __restrict__ bout,
    float* __restrict__ Ot)   // [NB][NROW][ODIM]
{
  const int tid   = threadIdx.x;
  const int lane  = tid & 63;
  const int wid   = tid >> 6;
  const int gbase = blockIdx.x * MG;

  __shared__ __align__(16) Smem s;

  if (tid < MG * EMB / 4) {
    const int g = tid >> 6, q = tid & 63;
    *reinterpret_cast<f32x4*>(&s.e[g][q * 4]) =
        *reinterpret_cast<const f32x4*>(&emb[(size_t)(gbase + g) * EMB + q * 4]);
  }
  __syncthreads();

  // init split-K: wid = k-eighth, lane = col j, all MG graphs
  {
    const int k0 = wid * 32, j = lane;
    float a[MG] = {0.f, 0.f, 0.f, 0.f};
    #pragma unroll
    for (int kk = 0; kk < 32; kk += 4) {
      float w[4];
      #pragma unroll
      for (int c = 0; c < 4; ++c) w[c] = W_emb[(k0 + kk + c) * HID + j];
      #pragma unroll
      for (int g = 0; g < MG; ++g) {
        const f32x4 ev = *reinterpret_cast<const f32x4*>(&s.e[g][k0 + kk]);
        a[g] = fmaf(ev[0], w[0], a[g]);
        a[g] = fmaf(ev[1], w[1], a[g]);
        a[g] = fmaf(ev[2], w[2], a[g]);
        a[g] = fmaf(ev[3], w[3], a[g]);
      }
    }
    #pragma unroll
    for (int g = 0; g < MG; ++g) s.red[wid][g][lane] = a[g];
  }
  __syncthreads();   // last barrier

  const int g = wid & 3, j = lane;
  float* OtG = Ot + (size_t)(gbase + g) * (NROW * ODIM);

  {
    float v = b_emb[j];
    #pragma unroll
    for (int kq = 0; kq < 8; ++kq) v += s.red[kq][g][j];
    if (wid < 4) s.X8s[g][0][j] = v;
    else         s.X8b[g][0][j] = v;
  }

  if (wid < 4) {
    // interior path: chain + O-row 8
    #pragma unroll
    for (int l = 0; l < 3; ++l) {
      const float* W = convW + l * HID * HID;
      float acc = 0.f;
      #pragma unroll
      for (int k0 = 0; k0 < HID; k0 += 4) {
        const f32x4 xv = *reinterpret_cast<const f32x4*>(&s.X8s[g][l][k0]);
        acc = fmaf(xv[0], W[(k0 + 0) * HID + j], acc);
        acc = fmaf(xv[1], W[(k0 + 1) * HID + j], acc);
        acc = fmaf(xv[2], W[(k0 + 2) * HID + j], acc);
        acc = fmaf(xv[3], W[(k0 + 3) * HID + j], acc);
      }
      s.X8s[g][l + 1][j] = fmaxf(acc + convB[l * HID + j], 0.f);
    }
    float a0 = bout[j], a1 = bout[j + 64];
    #pragma unroll
    for (int k0 = 0; k0 < HID; k0 += 4) {
      const f32x4 xv = *reinterpret_cast<const f32x4*>(&s.X8s[g][3][k0]);
      #pragma unroll
      for (int c = 0; c < 4; ++c) {
        a0 = fmaf(xv[c], Wout[(k0 + c) * ODIM + j], a0);
        a1 = fmaf(xv[c], Wout[(k0 + c) * ODIM + j + 64], a1);
      }
    }
    OtG[8 * ODIM + j]      = a0;
    OtG[8 * ODIM + 64 + j] = a1;
  } else {
    // boundary path
    boundary_layer<0, 0>(s, g, j, convW, convB);
    boundary_layer<1, 4>(s, g, j, convW, convB);
    boundary_layer<2, 6>(s, g, j, convW, convB);

    float aa[8], ab[8];
    #pragma unroll
    for (int r = 0; r < 8; ++r) { aa[r] = bout[j]; ab[r] = bout[j + 64]; }
    #pragma unroll
    for (int k0 = 0; k0 < HID; k0 += 4) {
      float w0[4], w1[4];
      #pragma unroll
      for (int c = 0; c < 4; ++c) {
        w0[c] = Wout[(k0 + c) * ODIM + j];
        w1[c] = Wout[(k0 + c) * ODIM + j + 64];
      }
      #pragma unroll
      for (int r = 0; r < 8; ++r) {
        const f32x4 xv = *reinterpret_cast<const f32x4*>(&s.Xb[g][r][k0]);
        #pragma unroll
        for (int c = 0; c < 4; ++c) {
          aa[r] = fmaf(xv[c], w0[c], aa[r]);
          ab[r] = fmaf(xv[c], w1[c], ab[r]);
        }
      }
    }
    #pragma unroll
    for (int r = 0; r < 8; ++r) {
      OtG[r * ODIM + j]      = aa[r];
      OtG[r * ODIM + 64 + j] = ab[r];
    }
  }
}

// ---------------- Kernel B: fill-style grid-stride streamer ----------------
// Flat f32x4 sweep of the whole 268 MB output, exactly like the 6.9 TB/s
// fill kernel's frontier: all waves' in-flight stores interleave across a
// rolling global window. Value gathered per element from the table (interior
// hot set = 2048 x 512 B = 1 MB, L2-resident).
__global__ __launch_bounds__(256) void bcast_gs(
    const float* __restrict__ Ot,
    float* __restrict__ out)
{
  const f32x4* Ot4  = reinterpret_cast<const f32x4*>(Ot);
  f32x4*       out4 = reinterpret_cast<f32x4*>(out);

  const int nth = NB * 256;                       // 524288 threads
  int idx4 = blockIdx.x * 256 + threadIdx.x;      // f32x4 index, 2^24 total

  #pragma unroll 8
  for (int it = 0; it < 32; ++it, idx4 += nth) {
    const int q     = idx4 & 31;                  // 16B slot within node row
    const int node  = (idx4 >> 5) & 255;
    const int graph = idx4 >> 13;
    const int row   = (node < 8) ? node : ((node > 247) ? (255 - node) : 8);
    out4[idx4] = Ot4[graph * (NROW * 32) + row * 32 + q];
  }
}

extern "C" void kernel_launch(void* const* d_in, const int* in_sizes, int n_in,
                              void* d_out, int out_size, void* d_ws, size_t ws_size,
                              hipStream_t stream) {
  const float* emb   = (const float*)d_in[0];
  const float* W_emb = (const float*)d_in[1];
  const float* b_emb = (const float*)d_in[2];
  const float* convW = (const float*)d_in[3];
  const float* convB = (const float*)d_in[4];
  const float* Wout  = (const float*)d_in[5];
  const float* bout  = (const float*)d_in[6];
  float* out = (float*)d_out;
  float* Ot  = (float*)d_ws;   // NB*NROW*ODIM f32 = 9.4 MB

  hipLaunchKernelGGL(compute_rows, dim3(NBLK), dim3(512), 0, stream,
                     emb, W_emb, b_emb, convW, convB, Wout, bout, Ot);
  hipLaunchKernelGGL(bcast_gs, dim3(NB), dim3(256), 0, stream, Ot, out);
}

// Round 9
// 74.088 us; speedup vs baseline: 1.0520x; 1.0520x over previous
//
#include <hip/hip_runtime.h>

// ASTDecoder: batched GCN on a fixed banded graph (i<->i+1, i<->i+2), 2048
// graphs x 256 nodes. Only 9 distinct rows/graph survive 3 layers (8 boundary
// + 1 interior; tail mirrors head). History: 102 -> 92 -> 78 -> 73 -> 65.6 ->
// 66.4 -> 77.9us. Write floor ~39us (fill: 6.9 TB/s at 10.5% occupancy,
// ~216 blocks, VGPR 8 -> ONE contiguous ~1MB frontier sweeping the buffer).
// R8's wide-frontier test was confounded (32 waves/CU + dependent gather +
// 10 VALU/store -> regressed). R9: kernel B exactly emulates fill: 256
// blocks x 256 threads flat grid-stride; with T=65536, idx = t + i*T keeps
// (node,q) INVARIANT per thread (graph advances by 8/iter), so row/q are
// computed once and each iteration is just {constant-stride L2 load, store}.
// Kernel A byte-identical to R7 (single-variable experiment).

#define NB   2048
#define EMB  256
#define HID  64
#define ODIM 128
#define NN   256
#define NROW 9
#define MG   4            // graphs per block (kernel A)
#define NBLK (NB / MG)

typedef float f32x4 __attribute__((ext_vector_type(4)));

__device__ __forceinline__ float dinvf(int j) {
  // deg: node0=3, node1=4, nodes 2..253=5 (mirror symmetric); only j<=9 used.
  if (j == 0) return 0.57735026918962576f;  // 1/sqrt(3)
  if (j == 1) return 0.5f;                  // 1/sqrt(4)
  return 0.44721359549995794f;              // 1/sqrt(5)
}

struct Smem {
  float e[MG][EMB];        // staged embeddings
  float red[8][MG][HID];   // init split-K partials
  float X8s[MG][4][HID];   // interior chain levels (interior waves)
  float X8b[MG][4][HID];   // boundary waves' private chain copy
  float Xb[MG][8][HID];    // boundary rows
};

// One boundary-path GCN layer (intra-wave dataflow only).
template <int L, int ND_IN>
__device__ __forceinline__ void boundary_layer(Smem& s, int g, int j,
                                               const float* __restrict__ convW,
                                               const float* __restrict__ convB) {
  const float* W  = convW + L * HID * HID;
  const float* bb = convB + L * HID;

  // interior-row chain step: g8 = X8^L @ W (col j), pre-bias/pre-relu
  float g8 = 0.f;
  #pragma unroll
  for (int k0 = 0; k0 < HID; k0 += 4) {
    const f32x4 xv = *reinterpret_cast<const f32x4*>(&s.X8b[g][L][k0]);
    g8 = fmaf(xv[0], W[(k0 + 0) * HID + j], g8);
    g8 = fmaf(xv[1], W[(k0 + 1) * HID + j], g8);
    g8 = fmaf(xv[2], W[(k0 + 2) * HID + j], g8);
    g8 = fmaf(xv[3], W[(k0 + 3) * HID + j], g8);
  }
  s.X8b[g][L + 1][j] = fmaxf(g8 + bb[j], 0.f);

  // boundary G rows (register accumulators)
  float accR[ND_IN > 0 ? ND_IN : 1];
  #pragma unroll
  for (int r = 0; r < (ND_IN > 0 ? ND_IN : 1); ++r) accR[r] = 0.f;
  if constexpr (ND_IN > 0) {
    #pragma unroll
    for (int k0 = 0; k0 < HID; k0 += 4) {
      float w[4];
      #pragma unroll
      for (int c = 0; c < 4; ++c) w[c] = W[(k0 + c) * HID + j];
      #pragma unroll
      for (int r = 0; r < ND_IN; ++r) {
        const f32x4 xv = *reinterpret_cast<const f32x4*>(&s.Xb[g][r][k0]);
        accR[r] = fmaf(xv[0], w[0], accR[r]);
        accR[r] = fmaf(xv[1], w[1], accR[r]);
        accR[r] = fmaf(xv[2], w[2], accR[r]);
        accR[r] = fmaf(xv[3], w[3], accR[r]);
      }
    }
  }

  // banded mix
  constexpr int NDN = (ND_IN + 2 < 4) ? 4 : (ND_IN + 2);
  float xnew[NDN];
  #pragma unroll
  for (int i = 0; i < NDN; ++i) {
    const float di = dinvf(i);
    float acc = 0.f;
    #pragma unroll
    for (int jj = (i >= 2 ? i - 2 : 0); jj <= i + 2; ++jj) {
      const float v = (jj < ND_IN) ? accR[jj] : g8;
      acc = fmaf(di * dinvf(jj), v, acc);
    }
    xnew[i] = fmaxf(acc + bb[j], 0.f);
  }
  #pragma unroll
  for (int i = 0; i < NDN; ++i) s.Xb[g][i][j] = xnew[i];
}

// ---------------- Kernel A: distinct-row table (unchanged from R7) ----------------
__global__ __launch_bounds__(512) void compute_rows(
    const float* __restrict__ emb,
    const float* __restrict__ W_emb,
    const float* __restrict__ b_emb,
    const float* __restrict__ convW,
    const float* __restrict__ convB,
    const float* __restrict__ Wout,
    const float* __restrict__ bout,
    float* __restrict__ Ot)   // [NB][NROW][ODIM]
{
  const int tid   = threadIdx.x;
  const int lane  = tid & 63;
  const int wid   = tid >> 6;
  const int gbase = blockIdx.x * MG;

  __shared__ __align__(16) Smem s;

  if (tid < MG * EMB / 4) {
    const int g = tid >> 6, q = tid & 63;
    *reinterpret_cast<f32x4*>(&s.e[g][q * 4]) =
        *reinterpret_cast<const f32x4*>(&emb[(size_t)(gbase + g) * EMB + q * 4]);
  }
  __syncthreads();

  // init split-K: wid = k-eighth, lane = col j, all MG graphs
  {
    const int k0 = wid * 32, j = lane;
    float a[MG] = {0.f, 0.f, 0.f, 0.f};
    #pragma unroll
    for (int kk = 0; kk < 32; kk += 4) {
      float w[4];
      #pragma unroll
      for (int c = 0; c < 4; ++c) w[c] = W_emb[(k0 + kk + c) * HID + j];
      #pragma unroll
      for (int g = 0; g < MG; ++g) {
        const f32x4 ev = *reinterpret_cast<const f32x4*>(&s.e[g][k0 + kk]);
        a[g] = fmaf(ev[0], w[0], a[g]);
        a[g] = fmaf(ev[1], w[1], a[g]);
        a[g] = fmaf(ev[2], w[2], a[g]);
        a[g] = fmaf(ev[3], w[3], a[g]);
      }
    }
    #pragma unroll
    for (int g = 0; g < MG; ++g) s.red[wid][g][lane] = a[g];
  }
  __syncthreads();   // last barrier

  const int g = wid & 3, j = lane;
  float* OtG = Ot + (size_t)(gbase + g) * (NROW * ODIM);

  {
    float v = b_emb[j];
    #pragma unroll
    for (int kq = 0; kq < 8; ++kq) v += s.red[kq][g][j];
    if (wid < 4) s.X8s[g][0][j] = v;
    else         s.X8b[g][0][j] = v;
  }

  if (wid < 4) {
    // interior path: chain + O-row 8
    #pragma unroll
    for (int l = 0; l < 3; ++l) {
      const float* W = convW + l * HID * HID;
      float acc = 0.f;
      #pragma unroll
      for (int k0 = 0; k0 < HID; k0 += 4) {
        const f32x4 xv = *reinterpret_cast<const f32x4*>(&s.X8s[g][l][k0]);
        acc = fmaf(xv[0], W[(k0 + 0) * HID + j], acc);
        acc = fmaf(xv[1], W[(k0 + 1) * HID + j], acc);
        acc = fmaf(xv[2], W[(k0 + 2) * HID + j], acc);
        acc = fmaf(xv[3], W[(k0 + 3) * HID + j], acc);
      }
      s.X8s[g][l + 1][j] = fmaxf(acc + convB[l * HID + j], 0.f);
    }
    float a0 = bout[j], a1 = bout[j + 64];
    #pragma unroll
    for (int k0 = 0; k0 < HID; k0 += 4) {
      const f32x4 xv = *reinterpret_cast<const f32x4*>(&s.X8s[g][3][k0]);
      #pragma unroll
      for (int c = 0; c < 4; ++c) {
        a0 = fmaf(xv[c], Wout[(k0 + c) * ODIM + j], a0);
        a1 = fmaf(xv[c], Wout[(k0 + c) * ODIM + j + 64], a1);
      }
    }
    OtG[8 * ODIM + j]      = a0;
    OtG[8 * ODIM + 64 + j] = a1;
  } else {
    // boundary path
    boundary_layer<0, 0>(s, g, j, convW, convB);
    boundary_layer<1, 4>(s, g, j, convW, convB);
    boundary_layer<2, 6>(s, g, j, convW, convB);

    float aa[8], ab[8];
    #pragma unroll
    for (int r = 0; r < 8; ++r) { aa[r] = bout[j]; ab[r] = bout[j + 64]; }
    #pragma unroll
    for (int k0 = 0; k0 < HID; k0 += 4) {
      float w0[4], w1[4];
      #pragma unroll
      for (int c = 0; c < 4; ++c) {
        w0[c] = Wout[(k0 + c) * ODIM + j];
        w1[c] = Wout[(k0 + c) * ODIM + j + 64];
      }
      #pragma unroll
      for (int r = 0; r < 8; ++r) {
        const f32x4 xv = *reinterpret_cast<const f32x4*>(&s.Xb[g][r][k0]);
        #pragma unroll
        for (int c = 0; c < 4; ++c) {
          aa[r] = fmaf(xv[c], w0[c], aa[r]);
          ab[r] = fmaf(xv[c], w1[c], ab[r]);
        }
      }
    }
    #pragma unroll
    for (int r = 0; r < 8; ++r) {
      OtG[r * ODIM + j]      = aa[r];
      OtG[r * ODIM + 64 + j] = ab[r];
    }
  }
}

// ---------------- Kernel B: fill-emulating streamer ----------------
// 256 blocks x 256 threads (1 block/CU, 4 waves/CU — fill runs at ~3.4).
// Flat grid-stride with T = 65536: thread's flat f32x4 index t + i*T keeps
// (node, q) invariant — graph advances by exactly 8 per iteration. So the
// source is a constant-stride (2304 f32x4 = 4608 B) independent L2 load and
// the body is {load, store, 2 pointer adds}: VGPR-tiny, one contiguous 1 MB
// store frontier sweeping the 268 MB buffer, exactly like fillBufferAligned.
__global__ __launch_bounds__(256) void bcast_fill(
    const float* __restrict__ Ot,
    float* __restrict__ out)
{
  const f32x4* Ot4  = reinterpret_cast<const f32x4*>(Ot);
  f32x4*       out4 = reinterpret_cast<f32x4*>(out);

  const int t    = blockIdx.x * 256 + threadIdx.x;  // 0..65535
  const int q    = t & 31;
  const int node = (t >> 5) & 255;
  const int g0   = t >> 13;                         // 0..7
  const int row  = (node < 8) ? node : ((node > 247) ? (255 - node) : 8);

  const f32x4* src = Ot4 + g0 * (NROW * 32) + row * 32 + q;  // +2304/iter
  f32x4*       dst = out4 + t;                               // +65536/iter

  #pragma unroll 8
  for (int it = 0; it < NB / 8; ++it) {       // 256 iterations
    *dst = *src;
    src += 8 * NROW * 32;   // next graph group (+8 graphs)
    dst += 65536;           // next 1 MB window
  }
}

extern "C" void kernel_launch(void* const* d_in, const int* in_sizes, int n_in,
                              void* d_out, int out_size, void* d_ws, size_t ws_size,
                              hipStream_t stream) {
  const float* emb   = (const float*)d_in[0];
  const float* W_emb = (const float*)d_in[1];
  const float* b_emb = (const float*)d_in[2];
  const float* convW = (const float*)d_in[3];
  const float* convB = (const float*)d_in[4];
  const float* Wout  = (const float*)d_in[5];
  const float* bout  = (const float*)d_in[6];
  float* out = (float*)d_out;
  float* Ot  = (float*)d_ws;   // NB*NROW*ODIM f32 = 9.4 MB

  hipLaunchKernelGGL(compute_rows, dim3(NBLK), dim3(512), 0, stream,
                     emb, W_emb, b_emb, convW, convB, Wout, bout, Ot);
  hipLaunchKernelGGL(bcast_fill, dim3(256), dim3(256), 0, stream, Ot, out);
}

// Round 10
// 64.538 us; speedup vs baseline: 1.2077x; 1.1480x over previous
//
#include <hip/hip_runtime.h>

// ASTDecoder: batched GCN on a fixed banded graph (i<->i+1, i<->i+2), 2048
// graphs x 256 nodes. Only 9 distinct rows/graph survive 3 layers (8 boundary
// + 1 interior; tail mirrors head). History: 102 -> 92 -> 78 -> 73 -> 65.6 ->
// 66.4 -> 77.9 -> 74.1us.
// R10 insight (fits ALL prior data): the write phase was ~6.6 TB/s all along;
// the hidden ~25us was WEIGHT RE-READS — every wave re-read its weight
// columns from L2 at 4B/lane (~150KB/wave x 12 waves x 512 blocks ~ 850MB of
// L2 traffic, serial before the first store). Fix: stage ALL weights in LDS
// once per block (MG=8, 256 blocks x 1024 threads, 1 block/CU, 141KB LDS),
// then R6's barrier-free wave-specialized flow: interior wave g streams 240
// nodes ~2us in; boundary wave g+8 computes under the store drain.

#define NB   2048
#define EMB  256
#define HID  64
#define ODIM 128
#define NN   256
#define MG   8            // graphs per block
#define NBLK (NB / MG)    // 256 blocks = 1/CU

typedef float f32x4 __attribute__((ext_vector_type(4)));

__device__ __forceinline__ float dinvf(int j) {
  // deg: node0=3, node1=4, nodes 2..253=5 (mirror symmetric); only j<=9 used.
  if (j == 0) return 0.57735026918962576f;  // 1/sqrt(3)
  if (j == 1) return 0.5f;                  // 1/sqrt(4)
  return 0.44721359549995794f;              // 1/sqrt(5)
}

struct Smem {
  float wbuf[20480];        // 80KB: phase01 = W_emb (16384); later convW(12288)+Wout(8192)
  float e[MG][EMB];         // 8KB
  float red[8][MG][HID];    // 16KB
  float X8s[MG][4][HID];    // 8KB  interior chain levels
  float X8b[MG][4][HID];    // 8KB  boundary waves' chain copy
  float Xb[MG][8][HID];     // 16KB boundary rows
  float O8[MG][ODIM];       // 4KB  interior output row (store bounce)
  float cb[3][HID];         // convB
  float be[HID];            // b_emb
  float bo[ODIM];           // bout
};                          // ~141.5KB -> 1 block/CU

// One boundary-path GCN layer; all weight reads from LDS, all dataflow
// intra-wave (lockstep, no barriers).
template <int L, int ND_IN>
__device__ __forceinline__ void boundary_layer(Smem& s, int g, int j) {
  const float* W = s.wbuf + L * HID * HID;   // LDS convW

  // interior-row chain step (pre-bias value needed for the mix)
  float g8 = 0.f;
  #pragma unroll
  for (int k0 = 0; k0 < HID; k0 += 4) {
    const f32x4 xv = *reinterpret_cast<const f32x4*>(&s.X8b[g][L][k0]);
    g8 = fmaf(xv[0], W[(k0 + 0) * HID + j], g8);
    g8 = fmaf(xv[1], W[(k0 + 1) * HID + j], g8);
    g8 = fmaf(xv[2], W[(k0 + 2) * HID + j], g8);
    g8 = fmaf(xv[3], W[(k0 + 3) * HID + j], g8);
  }
  s.X8b[g][L + 1][j] = fmaxf(g8 + s.cb[L][j], 0.f);

  // boundary G rows (register accumulators; Xb broadcast-read from LDS)
  float accR[ND_IN > 0 ? ND_IN : 1];
  #pragma unroll
  for (int r = 0; r < (ND_IN > 0 ? ND_IN : 1); ++r) accR[r] = 0.f;
  if constexpr (ND_IN > 0) {
    #pragma unroll
    for (int k0 = 0; k0 < HID; k0 += 4) {
      float w[4];
      #pragma unroll
      for (int c = 0; c < 4; ++c) w[c] = W[(k0 + c) * HID + j];
      #pragma unroll
      for (int r = 0; r < ND_IN; ++r) {
        const f32x4 xv = *reinterpret_cast<const f32x4*>(&s.Xb[g][r][k0]);
        accR[r] = fmaf(xv[0], w[0], accR[r]);
        accR[r] = fmaf(xv[1], w[1], accR[r]);
        accR[r] = fmaf(xv[2], w[2], accR[r]);
        accR[r] = fmaf(xv[3], w[3], accR[r]);
      }
    }
  }

  // banded mix
  constexpr int NDN = (ND_IN + 2 < 4) ? 4 : (ND_IN + 2);
  float xnew[NDN];
  #pragma unroll
  for (int i = 0; i < NDN; ++i) {
    const float di = dinvf(i);
    float acc = 0.f;
    #pragma unroll
    for (int jj = (i >= 2 ? i - 2 : 0); jj <= i + 2; ++jj) {
      const float v = (jj < ND_IN) ? accR[jj] : g8;
      acc = fmaf(di * dinvf(jj), v, acc);
    }
    xnew[i] = fmaxf(acc + s.cb[L][j], 0.f);
  }
  #pragma unroll
  for (int i = 0; i < NDN; ++i) s.Xb[g][i][j] = xnew[i];
}

__global__ __launch_bounds__(1024) void gcn_fused(
    const float* __restrict__ emb,
    const float* __restrict__ W_emb,
    const float* __restrict__ b_emb,
    const float* __restrict__ convW,
    const float* __restrict__ convB,
    const float* __restrict__ Wout,
    const float* __restrict__ bout,
    float* __restrict__ out)
{
  const int tid   = threadIdx.x;
  const int lane  = tid & 63;
  const int wid   = tid >> 6;          // 0..15
  const int gbase = blockIdx.x * MG;

  __shared__ __align__(16) Smem s;

  // ---- phase 0: stage W_emb (64KB), embeddings (8KB), biases ----
  {
    const f32x4* W4  = reinterpret_cast<const f32x4*>(W_emb);
    f32x4*       wb4 = reinterpret_cast<f32x4*>(s.wbuf);
    #pragma unroll
    for (int i = 0; i < 4; ++i) wb4[tid + i * 1024] = W4[tid + i * 1024];
    if (tid < 512) {
      const int g = tid >> 6, q = tid & 63;
      *reinterpret_cast<f32x4*>(&s.e[g][q * 4]) =
          *reinterpret_cast<const f32x4*>(&emb[(size_t)(gbase + g) * EMB + q * 4]);
    }
    if (tid < HID)                        s.be[tid] = b_emb[tid];
    else if (tid >= 64  && tid < 256)     { const int t = tid - 64; s.cb[t >> 6][t & 63] = convB[t]; }
    else if (tid >= 256 && tid < 384)     s.bo[tid - 256] = bout[tid - 256];
  }
  __syncthreads();

  // ---- phase 1: init split-K (waves 0..7, 32 k's each, all 8 graphs) ----
  if (wid < 8) {
    const int k0 = wid * 32, j = lane;
    float a[MG] = {};
    for (int kk = 0; kk < 32; ++kk) {
      const float w = s.wbuf[(k0 + kk) * HID + j];
      #pragma unroll
      for (int g = 0; g < MG; ++g) a[g] = fmaf(s.e[g][k0 + kk], w, a[g]);
    }
    #pragma unroll
    for (int g = 0; g < MG; ++g) s.red[wid][g][j] = a[g];
  }
  __syncthreads();

  // ---- phase 2: reduce into chain bases; stage convW+Wout over W_emb ----
  {
    const int g = wid & 7, j = lane;
    float v = s.be[j];
    #pragma unroll
    for (int q = 0; q < 8; ++q) v += s.red[q][g][j];
    if (wid < 8) s.X8s[g][0][j] = v;
    else         s.X8b[g][0][j] = v;
  }
  {
    const f32x4* cW4 = reinterpret_cast<const f32x4*>(convW);  // 3072 vec4
    const f32x4* Wo4 = reinterpret_cast<const f32x4*>(Wout);   // 2048 vec4
    f32x4*       wb4 = reinterpret_cast<f32x4*>(s.wbuf);
    #pragma unroll
    for (int i = 0; i < 5; ++i) {
      const int idx = tid + i * 1024;   // < 5120
      wb4[idx] = (idx < 3072) ? cW4[idx] : Wo4[idx - 3072];
    }
  }
  __syncthreads();   // last barrier — everything below is intra-wave

  const float* wo = s.wbuf + 12288;     // Wout in LDS [k*128 + col]
  const int g = wid & 7, j = lane;
  float* og = out + (size_t)(gbase + g) * NN * ODIM;

  if (wid < 8) {
    // ========== interior path (wave g): chain + O8 + 240-node stream ==========
    #pragma unroll
    for (int l = 0; l < 3; ++l) {
      const float* W = s.wbuf + l * HID * HID;
      float acc = 0.f;
      #pragma unroll
      for (int k0 = 0; k0 < HID; k0 += 4) {
        const f32x4 xv = *reinterpret_cast<const f32x4*>(&s.X8s[g][l][k0]);
        acc = fmaf(xv[0], W[(k0 + 0) * HID + j], acc);
        acc = fmaf(xv[1], W[(k0 + 1) * HID + j], acc);
        acc = fmaf(xv[2], W[(k0 + 2) * HID + j], acc);
        acc = fmaf(xv[3], W[(k0 + 3) * HID + j], acc);
      }
      s.X8s[g][l + 1][j] = fmaxf(acc + s.cb[l][j], 0.f);
    }
    float a0 = s.bo[j], a1 = s.bo[j + 64];
    #pragma unroll
    for (int k0 = 0; k0 < HID; k0 += 4) {
      const f32x4 xv = *reinterpret_cast<const f32x4*>(&s.X8s[g][3][k0]);
      #pragma unroll
      for (int c = 0; c < 4; ++c) {
        a0 = fmaf(xv[c], wo[(k0 + c) * ODIM + j], a0);
        a1 = fmaf(xv[c], wo[(k0 + c) * ODIM + j + 64], a1);
      }
    }
    s.O8[g][j]      = a0;
    s.O8[g][j + 64] = a1;

    // stream interior nodes 8..247 (same-wave LDS bounce for f32x4 layout)
    const int q = lane & 31, half = lane >> 5;
    const f32x4 vint = *reinterpret_cast<const f32x4*>(&s.O8[g][q * 4]);
    f32x4* og4 = reinterpret_cast<f32x4*>(og);
    #pragma unroll 8
    for (int it = 0; it < 120; ++it) {
      const int node = 8 + it * 2 + half;
      __builtin_nontemporal_store(vint, &og4[node * 32 + q]);
    }
  } else {
    // ========== boundary path (wave g+8): 8 rows + final + 16 nodes ==========
    boundary_layer<0, 0>(s, g, j);
    boundary_layer<1, 4>(s, g, j);
    boundary_layer<2, 6>(s, g, j);

    float aa[8], ab[8];
    #pragma unroll
    for (int r = 0; r < 8; ++r) { aa[r] = s.bo[j]; ab[r] = s.bo[j + 64]; }
    #pragma unroll
    for (int k0 = 0; k0 < HID; k0 += 4) {
      float w0[4], w1[4];
      #pragma unroll
      for (int c = 0; c < 4; ++c) {
        w0[c] = wo[(k0 + c) * ODIM + j];
        w1[c] = wo[(k0 + c) * ODIM + j + 64];
      }
      #pragma unroll
      for (int r = 0; r < 8; ++r) {
        const f32x4 xv = *reinterpret_cast<const f32x4*>(&s.Xb[g][r][k0]);
        #pragma unroll
        for (int c = 0; c < 4; ++c) {
          aa[r] = fmaf(xv[c], w0[c], aa[r]);
          ab[r] = fmaf(xv[c], w1[c], ab[r]);
        }
      }
    }

    // nodes 0..7 and mirrored 248..255; 256B-coalesced dword NT stores
    #pragma unroll
    for (int n = 0; n < 8; ++n) {
      __builtin_nontemporal_store(aa[n], &og[n * ODIM + j]);
      __builtin_nontemporal_store(ab[n], &og[n * ODIM + 64 + j]);
      __builtin_nontemporal_store(aa[n], &og[(255 - n) * ODIM + j]);
      __builtin_nontemporal_store(ab[n], &og[(255 - n) * ODIM + 64 + j]);
    }
  }
}

extern "C" void kernel_launch(void* const* d_in, const int* in_sizes, int n_in,
                              void* d_out, int out_size, void* d_ws, size_t ws_size,
                              hipStream_t stream) {
  const float* emb   = (const float*)d_in[0];
  const float* W_emb = (const float*)d_in[1];
  const float* b_emb = (const float*)d_in[2];
  const float* convW = (const float*)d_in[3];
  const float* convB = (const float*)d_in[4];
  const float* Wout  = (const float*)d_in[5];
  const float* bout  = (const float*)d_in[6];
  float* out = (float*)d_out;

  hipLaunchKernelGGL(gcn_fused, dim3(NBLK), dim3(1024), 0, stream,
                     emb, W_emb, b_emb, convW, convB, Wout, bout, out);
}